// Round 7
// baseline (264.244 us; speedup 1.0000x reference)
//
#include <hip/hip_runtime.h>
#include <stdint.h>

// Problem constants (fixed by reference)
#define N_IMG   16
#define C_IN    256
#define H_IN    32
#define W_IN    32
#define OH      30
#define OW      30
#define K_SEL   1152                   // C*KH*KW/2
#define OUTC    512
#define RY_TOT  (N_IMG * OH)           // 480 (n,y) rows
#define X_ELEMS (N_IMG * C_IN * H_IN * W_IN)   // 4194304
#define OUT_SP  (OH * OW)              // 900
#define CHW     (C_IN * H_IN * W_IN)   // 262144

#define TO      128                    // o-tile
#define TM      32                     // m-tile = 1 ry row x 32 xw  (R7: was 64)
#define NMT     RY_TOT                 // 480 m-tiles
#define NOT     (OUTC / TO)            // 4
#define BSTR    40                     // Bs row stride (shorts): 80B rows -> 16B-aligned b128
#define KITER   (K_SEL / 32)           // 36

typedef float f32x4  __attribute__((ext_vector_type(4)));
typedef short bf16x8 __attribute__((ext_vector_type(8)));   // 8 bf16 = 4 VGPRs

__device__ __forceinline__ unsigned short f2bf(float f) {   // fp32 -> bf16 RNE
    unsigned int u = __float_as_uint(f);
    u += 0x7FFFu + ((u >> 16) & 1u);
    return (unsigned short)(u >> 16);
}

// async global->LDS, 16B/lane; LDS dst wave-uniform base, HW adds lane*16.
__device__ __forceinline__ void gl_lds16(const void* g, void* lds) {
    __builtin_amdgcn_global_load_lds(
        (const __attribute__((address_space(1))) unsigned int*)g,
        (__attribute__((address_space(3))) unsigned int*)lds,
        16, 0, 0);
}

// ---------------------------------------------------------------------------
// Prep: koff decode + coalesced LDS-tile transpose w(K_SEL x OUTC fp32) ->
// wT(OUTC x K_SEL bf16). Grid (36 s-tiles, 16 o-tiles) x 256 thr.
// ---------------------------------------------------------------------------
__global__ void prep_kernel(const int* __restrict__ idx, const float* __restrict__ w,
                            int* __restrict__ koff, unsigned short* __restrict__ wT) {
    __shared__ float tile[32][33];                 // +1 pad: phase1 conflict-free
    const int bx = blockIdx.x, by = blockIdx.y, t = threadIdx.x;

    if (by == 0) {                                 // fold koff decode into first row
        int k = bx * 256 + t;
        if (k < K_SEL) {
            int v = idx[k];
            int c = v / 9, rem = v - c * 9;
            int i = rem / 3, j = rem - i * 3;
            koff[k] = c * (H_IN * W_IN) + i * W_IN + j;
        }
    }
    const int s0 = bx * 32, o0 = by * 32;
    const int oc = t & 31, sg = t >> 5;
#pragma unroll
    for (int i = 0; i < 4; ++i) {                  // coalesced 128B reads along o
        int sl = sg * 4 + i;
        tile[sl][oc] = w[(s0 + sl) * OUTC + o0 + oc];
    }
    __syncthreads();
    const int ol = t >> 3, sq = t & 7;             // write along s: coalesced
    unsigned int u0 = (unsigned int)f2bf(tile[sq * 4 + 0][ol]) |
                      ((unsigned int)f2bf(tile[sq * 4 + 1][ol]) << 16);
    unsigned int u1 = (unsigned int)f2bf(tile[sq * 4 + 2][ol]) |
                      ((unsigned int)f2bf(tile[sq * 4 + 3][ol]) << 16);
    uint2 pk; pk.x = u0; pk.y = u1;
    *reinterpret_cast<uint2*>(&wT[(size_t)(o0 + ol) * K_SEL + s0 + sq * 4]) = pk;
}

// ---------------------------------------------------------------------------
// Fused GEMM: out[n,o,y,x] = sum_k wT[o][k] * x[n, koff[k] + y*32 + xw]
// Tile 128o x 32m (ONE ry row), BK=32, 1920 blocks.
// R7: SPLIT-M concurrency experiment. R1/R3/R4 nulls (all pipes <=30%,
// occupancy ~28%, ~2.4 blocks/CU) => machine-level concurrency bound.
// TM 64->32 doubles the grid (960->1920) with DISJOINT outputs: no atomics,
// no memset -- exactly the R3/R4 harness envelope that ran clean (R5/R6's
// split-K + memset/atomics died at container level twice; abandoned).
// LDS 23KB + launch_bounds(256,6) -> up to 6 blocks/CU resident (was 4 cap,
// 2.4 actual). Per-step work halves: 6 VMEM (2 gl_lds + 4 gathers), 4 MFMA.
// Counted-vmcnt ledger (audited):
//   iter top: 6 outstanding (prev 2 gl_lds + 4 gathers); vmcnt(4) drains
//   the gl_lds -> As(kt) staged. Issue 2 gl_lds + 4 gathers -> 10;
//   vmcnt(6) drains prev gathers -> pack source ready. Barrier (lgkmcnt
//   only) every 2 steps; Bs 4-deep, pack distance 2 -> one barrier between
//   every pack->read and read->repack pair. o-siblings 480 apart,
//   480%8==0 -> same XCD -> wT/x L2 reuse preserved.
// ---------------------------------------------------------------------------
__global__ __launch_bounds__(256, 6)
void gemm_kernel(const unsigned short* __restrict__ wT, const float* __restrict__ x,
                 const int* __restrict__ koff, float* __restrict__ out) {
    __shared__ __align__(16) unsigned short As[TO * 32];       // single, wave-private rows
    __shared__ __align__(16) unsigned short Bs[4][TM * BSTR];  // quad buffer, 2.5KB each
    __shared__ int koS[K_SEL];

    const int t    = threadIdx.x;
    const int wave = t >> 6;
    const int lane = t & 63;
    const int quad = lane >> 4;
    const int lo   = lane & 15;

    const int bid  = blockIdx.x;
    const int mt   = bid % NMT;                    // ry row index 0..479
    const int ot   = bid / NMT;
    const int oBase = ot * TO;
    const int mBase = mt * TM;

    for (int i = t; i < K_SEL; i += 256) koS[i] = koff[i];

    const int xw  = t & 31;                        // spatial lane within ry row
    const int xwc = min(xw, 29);                   // clamp: all gathers in-bounds
    const int n_  = mt / 30, y_ = mt - n_ * 30;
    const int basex = n_ * CHW + y_ * W_IN + xwc;

    const int kq4 = t >> 5;                        // 0..7 -> 4 k's each
    const int ks  = kq4 * 4;

    // A staging: each wave owns 32 o-rows; 2 gl_lds16 of 1KB per k-tile.
    // Source pre-swizzled so linear LDS holds chunk c ^ ((row>>1)&3).
    const int lrow = lane >> 2, csw = (lane & 3) ^ ((lrow >> 1) & 3);
    const unsigned short* wrow0 =
        wT + (size_t)(oBase + wave * 32 + lrow) * K_SEL + csw * 8;
    const unsigned short* wrow1 =
        wT + (size_t)(oBase + wave * 32 + 16 + lrow) * K_SEL + csw * 8;
    unsigned short* lA0 = &As[(wave * 32) * 32];
    unsigned short* lA1 = lA0 + 16 * 32;

    // Loop-invariant addresses (same XOR applied on the chunk index).
    const int aswz = quad ^ ((lo >> 1) & 3);
    const unsigned short* aB = &As[(wave * 32 + lo) * 32 + aswz * 8];
    const unsigned short* bB[4] = {
        &Bs[0][lo * BSTR + quad * 8], &Bs[1][lo * BSTR + quad * 8],
        &Bs[2][lo * BSTR + quad * 8], &Bs[3][lo * BSTR + quad * 8] };
    unsigned short* bW[4] = {
        &Bs[0][xw * BSTR + ks], &Bs[1][xw * BSTR + ks],
        &Bs[2][xw * BSTR + ks], &Bs[3][xw * BSTR + ks] };

    __syncthreads();                               // koS ready (one-time drain ok)

    f32x4 acc[2][2] = {};
    float v[2][4];                                 // 2 rolling gather slots x 4 k's

    // ---- prologue: stage t0; gather t0,t1; pack t0; gather t2; pack t1 ----
    gl_lds16(wrow0, lA0);                          // VMEM 1-2
    gl_lds16(wrow1, lA1);
#pragma unroll
    for (int tl = 0; tl < 2; ++tl) {               // gathers t0 (VMEM 3-6), t1 (7-10)
        int4 k4 = *(const int4*)&koS[tl * 32 + ks];
#pragma unroll
        for (int j = 0; j < 4; ++j)
            v[tl][j] = x[basex + ((const int*)&k4)[j]];
    }
    asm volatile("s_waitcnt vmcnt(4)" ::: "memory");   // gl_lds(t0)+gathers(t0) done
    {
        unsigned int u0 = (unsigned int)f2bf(v[0][0]) | ((unsigned int)f2bf(v[0][1]) << 16);
        unsigned int u1 = (unsigned int)f2bf(v[0][2]) | ((unsigned int)f2bf(v[0][3]) << 16);
        uint2 pk; pk.x = u0; pk.y = u1;
        *reinterpret_cast<uint2*>(bW[0]) = pk;     // pack t0 -> Bs[0]
    }
    {                                              // gather t2 -> v[0] (4 more)
        int4 k4 = *(const int4*)&koS[2 * 32 + ks];
#pragma unroll
        for (int j = 0; j < 4; ++j)
            v[0][j] = x[basex + ((const int*)&k4)[j]];
    }
    asm volatile("s_waitcnt vmcnt(4)" ::: "memory");   // gathers(t1) done
    {
        unsigned int u0 = (unsigned int)f2bf(v[1][0]) | ((unsigned int)f2bf(v[1][1]) << 16);
        unsigned int u1 = (unsigned int)f2bf(v[1][2]) | ((unsigned int)f2bf(v[1][3]) << 16);
        uint2 pk; pk.x = u0; pk.y = u1;
        *reinterpret_cast<uint2*>(bW[1]) = pk;     // pack t1 -> Bs[1]
    }
    asm volatile("s_waitcnt lgkmcnt(0)" ::: "memory");
    __builtin_amdgcn_s_barrier();                  // Bs[0], Bs[1] visible

    // ---- main loop: manual x4 unroll, barrier every 2 k-steps ----
    // iter kt: read As(kt)+Bs[kt&3]; gl_lds(kt+1)->As; gather(kt+3)->v[(kt+1)&1];
    //          pack(kt+2) from v[kt&1] -> Bs[(kt+2)&3]; 4 MFMA.
#define KSTEP(KT, C, VR, VW) do {                                              \
    asm volatile("s_waitcnt vmcnt(4)" ::: "memory"); /* As(kt) staged */       \
    bf16x8 a0_ = *(const bf16x8*)(aB);                                         \
    bf16x8 a1_ = *(const bf16x8*)(aB + 16 * 32);                               \
    bf16x8 b0_ = *(const bf16x8*)(bB[C]);                                      \
    bf16x8 b1_ = *(const bf16x8*)(bB[C] + 16 * BSTR);                          \
    const int kg_ = ((KT) + 3 < KITER ? (KT) + 3 : KITER - 1) * 32;            \
    int4 k4_ = *(const int4*)&koS[kg_ + ks];                                   \
    asm volatile("s_waitcnt lgkmcnt(0)" ::: "memory"); /* frags+k4 in regs */  \
    __builtin_amdgcn_sched_barrier(0);                                         \
    const int k1_ = ((KT) + 1 < KITER ? (KT) + 1 : KITER - 1) * 32;            \
    gl_lds16(wrow0 + k1_, lA0);                    /* safe: As consumed */     \
    gl_lds16(wrow1 + k1_, lA1);                                                \
    _Pragma("unroll")                                                          \
    for (int j = 0; j < 4; ++j)                                                \
        v[VW][j] = x[basex + ((const int*)&k4_)[j]];                           \
    asm volatile("s_waitcnt vmcnt(6)" ::: "memory"); /* prev gathers done */   \
    {                                                                          \
        unsigned int u0_ = (unsigned int)f2bf(v[VR][0]) |                      \
                           ((unsigned int)f2bf(v[VR][1]) << 16);               \
        unsigned int u1_ = (unsigned int)f2bf(v[VR][2]) |                      \
                           ((unsigned int)f2bf(v[VR][3]) << 16);               \
        uint2 pk_; pk_.x = u0_; pk_.y = u1_;                                   \
        *reinterpret_cast<uint2*>(bW[((C) + 2) & 3]) = pk_;                    \
    }                                                                          \
    __builtin_amdgcn_s_setprio(1);                                             \
    acc[0][0] = __builtin_amdgcn_mfma_f32_16x16x32_bf16(a0_, b0_, acc[0][0], 0, 0, 0); \
    acc[0][1] = __builtin_amdgcn_mfma_f32_16x16x32_bf16(a0_, b1_, acc[0][1], 0, 0, 0); \
    acc[1][0] = __builtin_amdgcn_mfma_f32_16x16x32_bf16(a1_, b0_, acc[1][0], 0, 0, 0); \
    acc[1][1] = __builtin_amdgcn_mfma_f32_16x16x32_bf16(a1_, b1_, acc[1][1], 0, 0, 0); \
    __builtin_amdgcn_s_setprio(0);                                             \
} while (0)

    for (int kt0 = 0; kt0 < KITER; kt0 += 4) {     // 36 = 9 groups of 4
        KSTEP(kt0 + 0, 0, 0, 1);
        KSTEP(kt0 + 1, 1, 1, 0);
        asm volatile("s_waitcnt lgkmcnt(0)" ::: "memory");
        __builtin_amdgcn_s_barrier();              // packs(kt0+2,kt0+3) visible
        KSTEP(kt0 + 2, 2, 0, 1);
        KSTEP(kt0 + 3, 3, 1, 0);
        asm volatile("s_waitcnt lgkmcnt(0)" ::: "memory");
        __builtin_amdgcn_s_barrier();
    }
#undef KSTEP

    // Epilogue: D row = o (quad*4+r), col = m (lane&15); disjoint outputs.
#pragma unroll
    for (int ns = 0; ns < 2; ++ns) {
        const int mh  = mBase + ns * 16 + lo;
        const int xwe = mh & 31;
        if (xwe < OW) {
            const size_t ob = (size_t)n_ * (OUTC * OUT_SP) + (size_t)y_ * OW + xwe;
#pragma unroll
            for (int ms = 0; ms < 2; ++ms) {
                const int o0 = oBase + wave * 32 + ms * 16 + quad * 4;
#pragma unroll
                for (int r = 0; r < 4; ++r)
                    out[ob + (size_t)(o0 + r) * OUT_SP] = acc[ms][ns][r];
            }
        }
    }
}

// ---------------------------------------------------------------------------
extern "C" void kernel_launch(void* const* d_in, const int* in_sizes, int n_in,
                              void* d_out, int out_size, void* d_ws, size_t ws_size,
                              hipStream_t stream) {
    const float* x   = (const float*)d_in[0];
    const float* w   = (const float*)d_in[1];
    const int*   idx = (const int*)d_in[2];
    float*       out = (float*)d_out;

    // ws layout: koff 4608B | wT bf16 1179648B  (~1.2 MB total)
    char* ws = (char*)d_ws;
    int*            koff = (int*)ws;
    unsigned short* wT   = (unsigned short*)(ws + 4608);

    prep_kernel<<<dim3(K_SEL / 32, OUTC / 32), dim3(256), 0, stream>>>(idx, w, koff, wT);
    gemm_kernel<<<dim3(NMT * NOT), dim3(256), 0, stream>>>(wT, x, koff, out);
}

// Round 8
// 130.980 us; speedup vs baseline: 2.0174x; 2.0174x over previous
//
#include <hip/hip_runtime.h>
#include <stdint.h>

// Problem constants (fixed by reference)
#define N_IMG   16
#define C_IN    256
#define H_IN    32
#define W_IN    32
#define OH      30
#define OW      30
#define K_SEL   1152                   // C*KH*KW/2
#define OUTC    512
#define RY_TOT  (N_IMG * OH)           // 480 (n,y) rows
#define M_HAT   (RY_TOT * 32)          // 15360 = padded M (ow 30 -> 32)
#define X_ELEMS (N_IMG * C_IN * H_IN * W_IN)   // 4194304
#define OUT_SP  (OH * OW)              // 900
#define CHW     (C_IN * H_IN * W_IN)   // 262144

#define TO      128                    // o-tile
#define TM      64                     // m-tile = 2 ry rows x 32 xw
#define NMT     (M_HAT / TM)           // 240
#define NOT     (OUTC / TO)            // 4
#define BSTR    40                     // Bs row stride (shorts): 80B rows -> 16B-aligned b128
#define KITER   (K_SEL / 32)           // 36

typedef float f32x4  __attribute__((ext_vector_type(4)));
typedef short bf16x8 __attribute__((ext_vector_type(8)));   // 8 bf16 = 4 VGPRs

__device__ __forceinline__ unsigned short f2bf(float f) {   // fp32 -> bf16 RNE
    unsigned int u = __float_as_uint(f);
    u += 0x7FFFu + ((u >> 16) & 1u);
    return (unsigned short)(u >> 16);
}

// async global->LDS, 16B/lane; LDS dst wave-uniform base, HW adds lane*16.
__device__ __forceinline__ void gl_lds16(const void* g, void* lds) {
    __builtin_amdgcn_global_load_lds(
        (const __attribute__((address_space(1))) unsigned int*)g,
        (__attribute__((address_space(3))) unsigned int*)lds,
        16, 0, 0);
}

// ---------------------------------------------------------------------------
// Prep: koff decode + coalesced LDS-tile transpose w(K_SEL x OUTC fp32) ->
// wT(OUTC x K_SEL bf16). Grid (36 s-tiles, 16 o-tiles) x 256 thr.
// ---------------------------------------------------------------------------
__global__ void prep_kernel(const int* __restrict__ idx, const float* __restrict__ w,
                            int* __restrict__ koff, unsigned short* __restrict__ wT) {
    __shared__ float tile[32][33];                 // +1 pad: phase1 conflict-free
    const int bx = blockIdx.x, by = blockIdx.y, t = threadIdx.x;

    if (by == 0) {                                 // fold koff decode into first row
        int k = bx * 256 + t;
        if (k < K_SEL) {
            int v = idx[k];
            int c = v / 9, rem = v - c * 9;
            int i = rem / 3, j = rem - i * 3;
            koff[k] = c * (H_IN * W_IN) + i * W_IN + j;
        }
    }
    const int s0 = bx * 32, o0 = by * 32;
    const int oc = t & 31, sg = t >> 5;
#pragma unroll
    for (int i = 0; i < 4; ++i) {                  // coalesced 128B reads along o
        int sl = sg * 4 + i;
        tile[sl][oc] = w[(s0 + sl) * OUTC + o0 + oc];
    }
    __syncthreads();
    const int ol = t >> 3, sq = t & 7;             // write along s: coalesced
    unsigned int u0 = (unsigned int)f2bf(tile[sq * 4 + 0][ol]) |
                      ((unsigned int)f2bf(tile[sq * 4 + 1][ol]) << 16);
    unsigned int u1 = (unsigned int)f2bf(tile[sq * 4 + 2][ol]) |
                      ((unsigned int)f2bf(tile[sq * 4 + 3][ol]) << 16);
    uint2 pk; pk.x = u0; pk.y = u1;
    *reinterpret_cast<uint2*>(&wT[(size_t)(o0 + ol) * K_SEL + s0 + sq * 4]) = pk;
}

// ---------------------------------------------------------------------------
// Fused GEMM: out[n,o,y,x] = sum_k wT[o][k] * x[n, koff[k] + y*32 + xw]
// Tile 128o x 64m, BK=32, 960 blocks (R4 envelope: no atomics, no memset).
// R8 theory: R7 showed occupancy was NOT the limiter (54% occ, 204us) but
// L2 locality is; R4's 940cy/step == one x-gather round trip (L2-miss ->
// L3) with gather pipeline depth 1. Two levers:
//  * gather depth 2: v[4] slots, tile T gathered at step T-4, packed at
//    T-2. Single vmcnt(8) per step drains exactly {gl_lds(kt),
//    gathers(kt+2)} by issue order [gl, ga] (ledger below).
//  * XCD swizzle: bid%8 -> image-pair. Each XCD's blocks share 2 images
//    of x (2.1MB < 4MB L2) -> gathers become L2 hits (~200cy).
// Ledger (steady state, 10 VMEM/step issued as [2 gl_lds, 8 gathers]):
//   top of kt outstanding = ga(t kt+2)@kt-2 [8] + gl(t kt)@kt-1 [2] +
//   ga(t kt+3)@kt-1 [8] = 18. vmcnt(8) keeps 8 newest = ga(kt+3); drains
//   gl(kt) (As ready) + ga(kt+2) (pack source ready). Issue 2+8 -> 18.
//   Gather issue->wait distance = 2 full steps.
// Bs 4-deep, pack(kt+2)@kt, read@kt+2, barrier every 2 steps between all
// pack->read and read->repack pairs (unchanged from R4, ran correct).
// ---------------------------------------------------------------------------
__global__ __launch_bounds__(256, 4)
void gemm_kernel(const unsigned short* __restrict__ wT, const float* __restrict__ x,
                 const int* __restrict__ koff, float* __restrict__ out) {
    __shared__ __align__(16) unsigned short As[TO * 32];       // single, wave-private rows
    __shared__ __align__(16) unsigned short Bs[4][TM * BSTR];  // quad buffer
    __shared__ int koS[K_SEL];

    const int t    = threadIdx.x;
    const int wave = t >> 6;
    const int lane = t & 63;
    const int quad = lane >> 4;
    const int lo   = lane & 15;

    // XCD-locality decode: xcd = bid%8 (dispatch round-robin heuristic).
    // Each XCD gets 2 images (x slice 2.1MB -> L2-resident gathers).
    const int bid = blockIdx.x;
    const int g   = bid & 7;                       // xcd
    const int h   = bid >> 3;                      // 0..119
    const int nimg = g + 8 * (h & 1);              // image 0..15
    const int h2  = h >> 1;                        // 0..59
    const int mtl = h2 % 15;                       // 0..14 (15 mt per image)
    const int ot  = h2 / 15;                       // 0..3
    const int mt  = nimg * 15 + mtl;               // 0..239
    const int oBase = ot * TO;
    const int mBase = mt * TM;

    for (int i = t; i < K_SEL; i += 256) koS[i] = koff[i];

    const int xw  = t & 31;                        // spatial lane within ry row
    const int xwc = min(xw, 29);                   // clamp: all gathers in-bounds
    int basex[2];
#pragma unroll
    for (int ry = 0; ry < 2; ++ry) {
        int ryg = mt * 2 + ry;
        int n = ryg / 30, y = ryg - n * 30;
        basex[ry] = n * CHW + y * W_IN + xwc;
    }

    const int kq4 = t >> 5;                        // 0..7 -> 4 k's each
    const int ks  = kq4 * 4;

    // A staging: each wave owns 32 o-rows; 2 gl_lds16 of 1KB per k-tile.
    // Source pre-swizzled so linear LDS holds chunk c ^ ((row>>1)&3).
    const int lrow = lane >> 2, csw = (lane & 3) ^ ((lrow >> 1) & 3);
    const unsigned short* wrow0 =
        wT + (size_t)(oBase + wave * 32 + lrow) * K_SEL + csw * 8;
    const unsigned short* wrow1 =
        wT + (size_t)(oBase + wave * 32 + 16 + lrow) * K_SEL + csw * 8;
    unsigned short* lA0 = &As[(wave * 32) * 32];
    unsigned short* lA1 = lA0 + 16 * 32;

    // Loop-invariant addresses (same XOR applied on the chunk index).
    const int aswz = quad ^ ((lo >> 1) & 3);
    const unsigned short* aB = &As[(wave * 32 + lo) * 32 + aswz * 8];
    const unsigned short* bB[4] = {
        &Bs[0][lo * BSTR + quad * 8], &Bs[1][lo * BSTR + quad * 8],
        &Bs[2][lo * BSTR + quad * 8], &Bs[3][lo * BSTR + quad * 8] };
    unsigned short* bW[4] = {
        &Bs[0][xw * BSTR + ks], &Bs[1][xw * BSTR + ks],
        &Bs[2][xw * BSTR + ks], &Bs[3][xw * BSTR + ks] };

    __syncthreads();                               // koS ready (one-time drain ok)

    f32x4 acc[2][4] = {};
    float v[4][2][4];                              // tile T lives in v[T&3]

#define GATHER(TL, SLOT) do {                                                  \
    int4 k4 = *(const int4*)&koS[(TL) * 32 + ks];                              \
    _Pragma("unroll")                                                          \
    for (int ry = 0; ry < 2; ++ry)                                             \
        _Pragma("unroll")                                                      \
        for (int j = 0; j < 4; ++j)                                            \
            v[SLOT][ry][j] = x[basex[ry] + ((const int*)&k4)[j]];              \
} while (0)

#define PACK(SLOT, DST) do {                                                   \
    _Pragma("unroll")                                                          \
    for (int ry = 0; ry < 2; ++ry) {                                           \
        unsigned int u0_ = (unsigned int)f2bf(v[SLOT][ry][0]) |                \
                           ((unsigned int)f2bf(v[SLOT][ry][1]) << 16);         \
        unsigned int u1_ = (unsigned int)f2bf(v[SLOT][ry][2]) |                \
                           ((unsigned int)f2bf(v[SLOT][ry][3]) << 16);         \
        uint2 pk_; pk_.x = u0_; pk_.y = u1_;                                   \
        *reinterpret_cast<uint2*>(bW[DST] + ry * 32 * BSTR) = pk_;             \
    }                                                                          \
} while (0)

    // ---- prologue: establish the 18-outstanding invariant for step 0 ----
    GATHER(0, 0);                                  // 8
    GATHER(1, 1);                                  // 16
    asm volatile("s_waitcnt vmcnt(8)" ::: "memory");   // ga(t0) done
    PACK(0, 0);                                    // t0 -> Bs[0]
    asm volatile("s_waitcnt vmcnt(0)" ::: "memory");   // ga(t1) done
    PACK(1, 1);                                    // t1 -> Bs[1]
    GATHER(2, 2);                                  // ga(t2): ops 1-8
    gl_lds16(wrow0, lA0);                          // gl(t0): ops 9-10
    gl_lds16(wrow1, lA1);
    GATHER(3, 3);                                  // ga(t3): ops 11-18
    asm volatile("s_waitcnt lgkmcnt(0)" ::: "memory");
    __builtin_amdgcn_s_barrier();                  // Bs[0], Bs[1] visible

    // ---- main loop: x4 unroll, barrier every 2 k-steps ----
    // step kt (C=kt&3): vmcnt(8) [As(kt)+pack-source ready]; read frags;
    // gl_lds(kt+1); gather(kt+4)->v[C]; pack(kt+2) from v[(C+2)&3]; 8 MFMA.
#define KSTEP(KT, C) do {                                                      \
    asm volatile("s_waitcnt vmcnt(8)" ::: "memory");                           \
    bf16x8 a0_ = *(const bf16x8*)(aB);                                         \
    bf16x8 a1_ = *(const bf16x8*)(aB + 16 * 32);                               \
    bf16x8 b0_ = *(const bf16x8*)(bB[C]);                                      \
    bf16x8 b1_ = *(const bf16x8*)(bB[C] + 16 * BSTR);                          \
    bf16x8 b2_ = *(const bf16x8*)(bB[C] + 32 * BSTR);                          \
    bf16x8 b3_ = *(const bf16x8*)(bB[C] + 48 * BSTR);                          \
    asm volatile("s_waitcnt lgkmcnt(0)" ::: "memory"); /* frags in regs */     \
    __builtin_amdgcn_sched_barrier(0);                                         \
    const int k1_ = ((KT) + 1 < KITER ? (KT) + 1 : KITER - 1) * 32;            \
    gl_lds16(wrow0 + k1_, lA0);                    /* safe: As consumed */     \
    gl_lds16(wrow1 + k1_, lA1);                                                \
    GATHER(((KT) + 4 < KITER ? (KT) + 4 : KITER - 1), C);                      \
    PACK((C + 2) & 3, (C + 2) & 3);                /* tile kt+2 -> Bs */       \
    __builtin_amdgcn_s_setprio(1);                                             \
    acc[0][0] = __builtin_amdgcn_mfma_f32_16x16x32_bf16(a0_, b0_, acc[0][0], 0, 0, 0); \
    acc[0][1] = __builtin_amdgcn_mfma_f32_16x16x32_bf16(a0_, b1_, acc[0][1], 0, 0, 0); \
    acc[0][2] = __builtin_amdgcn_mfma_f32_16x16x32_bf16(a0_, b2_, acc[0][2], 0, 0, 0); \
    acc[0][3] = __builtin_amdgcn_mfma_f32_16x16x32_bf16(a0_, b3_, acc[0][3], 0, 0, 0); \
    acc[1][0] = __builtin_amdgcn_mfma_f32_16x16x32_bf16(a1_, b0_, acc[1][0], 0, 0, 0); \
    acc[1][1] = __builtin_amdgcn_mfma_f32_16x16x32_bf16(a1_, b1_, acc[1][1], 0, 0, 0); \
    acc[1][2] = __builtin_amdgcn_mfma_f32_16x16x32_bf16(a1_, b2_, acc[1][2], 0, 0, 0); \
    acc[1][3] = __builtin_amdgcn_mfma_f32_16x16x32_bf16(a1_, b3_, acc[1][3], 0, 0, 0); \
    __builtin_amdgcn_s_setprio(0);                                             \
} while (0)

    for (int kt0 = 0; kt0 < KITER; kt0 += 4) {     // 36 = 9 groups of 4
        KSTEP(kt0 + 0, 0);
        KSTEP(kt0 + 1, 1);
        asm volatile("s_waitcnt lgkmcnt(0)" ::: "memory");
        __builtin_amdgcn_s_barrier();              // packs(kt0+2,kt0+3) visible
        KSTEP(kt0 + 2, 2);
        KSTEP(kt0 + 3, 3);
        asm volatile("s_waitcnt lgkmcnt(0)" ::: "memory");
        __builtin_amdgcn_s_barrier();
    }
#undef KSTEP
#undef GATHER
#undef PACK

    // Epilogue: D row = o (quad*4+r), col = m (lane&15); disjoint outputs.
#pragma unroll
    for (int ns = 0; ns < 4; ++ns) {
        const int mh  = mBase + ns * 16 + lo;
        const int xwe = mh & 31;
        const int ryg = mh >> 5;
        const int n = ryg / 30, y = ryg - n * 30;
        if (xwe < OW) {
            const size_t ob = (size_t)n * (OUTC * OUT_SP) + (size_t)y * OW + xwe;
#pragma unroll
            for (int ms = 0; ms < 2; ++ms) {
                const int o0 = oBase + wave * 32 + ms * 16 + quad * 4;
#pragma unroll
                for (int r = 0; r < 4; ++r)
                    out[ob + (size_t)(o0 + r) * OUT_SP] = acc[ms][ns][r];
            }
        }
    }
}

// ---------------------------------------------------------------------------
extern "C" void kernel_launch(void* const* d_in, const int* in_sizes, int n_in,
                              void* d_out, int out_size, void* d_ws, size_t ws_size,
                              hipStream_t stream) {
    const float* x   = (const float*)d_in[0];
    const float* w   = (const float*)d_in[1];
    const int*   idx = (const int*)d_in[2];
    float*       out = (float*)d_out;

    // ws layout: koff 4608B | wT bf16 1179648B  (~1.2 MB total)
    char* ws = (char*)d_ws;
    int*            koff = (int*)ws;
    unsigned short* wT   = (unsigned short*)(ws + 4608);

    prep_kernel<<<dim3(K_SEL / 32, OUTC / 32), dim3(256), 0, stream>>>(idx, w, koff, wT);
    gemm_kernel<<<dim3(NMT * NOT), dim3(256), 0, stream>>>(wT, x, koff, out);
}

// Round 9
// 114.251 us; speedup vs baseline: 2.3128x; 1.1464x over previous
//
#include <hip/hip_runtime.h>
#include <stdint.h>

// Problem constants (fixed by reference)
#define N_IMG   16
#define C_IN    256
#define H_IN    32
#define W_IN    32
#define OH      30
#define OW      30
#define K_SEL   1152                   // C*KH*KW/2
#define OUTC    512
#define RY_TOT  (N_IMG * OH)           // 480 (n,y) rows
#define M_HAT   (RY_TOT * 32)          // 15360 = padded M (ow 30 -> 32)
#define X_ELEMS (N_IMG * C_IN * H_IN * W_IN)   // 4194304
#define OUT_SP  (OH * OW)              // 900
#define CHW     (C_IN * H_IN * W_IN)   // 262144

#define TO      256                    // o-tile (R9: was 128) - 2x MFMA per gather
#define TM      64                     // m-tile = 2 ry rows x 32 xw
#define NMT     (M_HAT / TM)           // 240
#define NOT     (OUTC / TO)            // 2
#define BSTR    40                     // Bs row stride (shorts): 80B rows -> 16B-aligned b128
#define KITER   (K_SEL / 32)           // 36

typedef float f32x4  __attribute__((ext_vector_type(4)));
typedef short bf16x8 __attribute__((ext_vector_type(8)));   // 8 bf16 = 4 VGPRs

__device__ __forceinline__ unsigned short f2bf(float f) {   // fp32 -> bf16 RNE
    unsigned int u = __float_as_uint(f);
    u += 0x7FFFu + ((u >> 16) & 1u);
    return (unsigned short)(u >> 16);
}

// async global->LDS, 16B/lane; LDS dst wave-uniform base, HW adds lane*16.
__device__ __forceinline__ void gl_lds16(const void* g, void* lds) {
    __builtin_amdgcn_global_load_lds(
        (const __attribute__((address_space(1))) unsigned int*)g,
        (__attribute__((address_space(3))) unsigned int*)lds,
        16, 0, 0);
}

// ---------------------------------------------------------------------------
// Prep: koff decode + coalesced LDS-tile transpose w(K_SEL x OUTC fp32) ->
// wT(OUTC x K_SEL bf16). Grid (36 s-tiles, 16 o-tiles) x 256 thr.
// ---------------------------------------------------------------------------
__global__ void prep_kernel(const int* __restrict__ idx, const float* __restrict__ w,
                            int* __restrict__ koff, unsigned short* __restrict__ wT) {
    __shared__ float tile[32][33];                 // +1 pad: phase1 conflict-free
    const int bx = blockIdx.x, by = blockIdx.y, t = threadIdx.x;

    if (by == 0) {                                 // fold koff decode into first row
        int k = bx * 256 + t;
        if (k < K_SEL) {
            int v = idx[k];
            int c = v / 9, rem = v - c * 9;
            int i = rem / 3, j = rem - i * 3;
            koff[k] = c * (H_IN * W_IN) + i * W_IN + j;
        }
    }
    const int s0 = bx * 32, o0 = by * 32;
    const int oc = t & 31, sg = t >> 5;
#pragma unroll
    for (int i = 0; i < 4; ++i) {                  // coalesced 128B reads along o
        int sl = sg * 4 + i;
        tile[sl][oc] = w[(s0 + sl) * OUTC + o0 + oc];
    }
    __syncthreads();
    const int ol = t >> 3, sq = t & 7;             // write along s: coalesced
    unsigned int u0 = (unsigned int)f2bf(tile[sq * 4 + 0][ol]) |
                      ((unsigned int)f2bf(tile[sq * 4 + 1][ol]) << 16);
    unsigned int u1 = (unsigned int)f2bf(tile[sq * 4 + 2][ol]) |
                      ((unsigned int)f2bf(tile[sq * 4 + 3][ol]) << 16);
    uint2 pk; pk.x = u0; pk.y = u1;
    *reinterpret_cast<uint2*>(&wT[(size_t)(o0 + ol) * K_SEL + s0 + sq * 4]) = pk;
}

// ---------------------------------------------------------------------------
// Fused GEMM: out[n,o,y,x] = sum_k wT[o][k] * x[n, koff[k] + y*32 + xw]
// Tile 256o x 64m, BK=32, 480 blocks.
// R9 theory: 8 rounds show the 52us R3 attractor is insensitive to schedule
// (R1/R3/R4 nulls) and hypersensitive to locality (R7 +300%, R8 +30%).
// The equilibrium is the x-gather service loop: each x row fetched once per
// ot-sibling, and each step's gather+pack feeds only 8 MFMA/wave. Fix by
// AMORTIZATION, not rescheduling: TO=128->256. Same gathers per wave-step
// now feed 16 MFMA; per-XCD x-gather L2 traffic halves (2 ot-siblings
// instead of 4; 240%8==0 keeps them same-XCD). Skeleton is byte-level R3
// (best measured, 51.5us): depth-1 gather, As dbuf (4 gl_lds/wave/step),
// Bs 2-deep, one barrier/step, counted vmcnt.
// Ledger: 12 VMEM/step (4 gl_lds + 8 gathers). vmcnt(12) at pack point
// drains exactly prev-step's gl(kt) (As[p] staged) + ga(kt+1) (pack
// source); this step's 12 stay in flight across the barrier.
// Prologue: ga(t0)[8], vmcnt(0), pack t0; gl(t0)[4]+ga(t1)[8] -> 12
// outstanding = loop-entry invariant. Tail clamps keep counts uniform
// (dup loads into never-read buffers, same as R3 which passed).
// LDS 47KB; launch_bounds(256,2): grid gives ~2 blocks/CU (8 waves).
// ---------------------------------------------------------------------------
__global__ __launch_bounds__(256, 2)
void gemm_kernel(const unsigned short* __restrict__ wT, const float* __restrict__ x,
                 const int* __restrict__ koff, float* __restrict__ out) {
    __shared__ __align__(16) unsigned short As[2][TO * 32];    // rows = o-local, k-contig
    __shared__ __align__(16) unsigned short Bs[2][TM * BSTR];  // rows = m-local, padded
    __shared__ int koS[K_SEL];

    const int t    = threadIdx.x;
    const int wave = t >> 6;
    const int lane = t & 63;
    const int quad = lane >> 4;
    const int lo   = lane & 15;

    const int bid = blockIdx.x;
    const int mt  = bid % NMT;                     // consecutive bids -> consecutive mt
    const int ot  = bid / NMT;                     // ot-siblings 240 apart -> same XCD
    const int oBase = ot * TO;
    const int mBase = mt * TM;

    for (int i = t; i < K_SEL; i += 256) koS[i] = koff[i];

    const int xw  = t & 31;                        // spatial lane within ry row
    const int xwc = min(xw, 29);                   // clamp: all gathers in-bounds (R4-verified)
    int basex[2];
#pragma unroll
    for (int ry = 0; ry < 2; ++ry) {
        int ryg = mt * 2 + ry;
        int n = ryg / 30, y = ryg - n * 30;
        basex[ry] = n * CHW + y * W_IN + xwc;
    }

    const int kq4 = t >> 5;                        // 0..7 -> 4 k's each
    const int ks  = kq4 * 4;

    // A staging: each wave owns 64 o-rows; 4 gl_lds16 of 1KB each per buffer.
    // Source pre-swizzled so linear LDS holds chunk c ^ ((row>>1)&3).
    const int lrow = lane >> 2, csw = (lane & 3) ^ ((lrow >> 1) & 3);
    const unsigned short* wrow[4];
#pragma unroll
    for (int i = 0; i < 4; ++i)
        wrow[i] = wT + (size_t)(oBase + wave * 64 + i * 16 + lrow) * K_SEL + csw * 8;
    unsigned short* lA[2][4];
#pragma unroll
    for (int b = 0; b < 2; ++b)
#pragma unroll
        for (int i = 0; i < 4; ++i)
            lA[b][i] = &As[b][(wave * 64 + i * 16) * 32];

    // Loop-invariant read addresses (same XOR applied on the chunk index).
    const int aswz = quad ^ ((lo >> 1) & 3);
    const unsigned short* aB[2] = {
        &As[0][(wave * 64 + lo) * 32 + aswz * 8],
        &As[1][(wave * 64 + lo) * 32 + aswz * 8] };
    const unsigned short* bB[2] = {
        &Bs[0][lo * BSTR + quad * 8],
        &Bs[1][lo * BSTR + quad * 8] };
    unsigned short* bW[2] = {
        &Bs[0][xw * BSTR + ks],
        &Bs[1][xw * BSTR + ks] };

    __syncthreads();                               // koS ready (one-time drain ok)

    f32x4 acc[4][4] = {};
    float v[2][2][4];                              // v[tile&1][ry][j]

    // ---- prologue ----
    {
        int4 k4 = *(const int4*)&koS[ks];          // gathers t0 (8)
#pragma unroll
        for (int ry = 0; ry < 2; ++ry)
#pragma unroll
            for (int j = 0; j < 4; ++j)
                v[0][ry][j] = x[basex[ry] + ((const int*)&k4)[j]];
    }
    asm volatile("s_waitcnt vmcnt(0)" ::: "memory");
#pragma unroll
    for (int ry = 0; ry < 2; ++ry) {               // pack t0 -> Bs[0]
        unsigned int u0 = (unsigned int)f2bf(v[0][ry][0]) |
                          ((unsigned int)f2bf(v[0][ry][1]) << 16);
        unsigned int u1 = (unsigned int)f2bf(v[0][ry][2]) |
                          ((unsigned int)f2bf(v[0][ry][3]) << 16);
        uint2 pk; pk.x = u0; pk.y = u1;
        *reinterpret_cast<uint2*>(bW[0] + ry * 32 * BSTR) = pk;
    }
#pragma unroll
    for (int i = 0; i < 4; ++i) gl_lds16(wrow[i], lA[0][i]);   // gl(t0): 4
    {
        int4 k4 = *(const int4*)&koS[32 + ks];     // gathers t1 (8) -> 12 outstanding
#pragma unroll
        for (int ry = 0; ry < 2; ++ry)
#pragma unroll
            for (int j = 0; j < 4; ++j)
                v[1][ry][j] = x[basex[ry] + ((const int*)&k4)[j]];
    }
    asm volatile("s_waitcnt lgkmcnt(0)" ::: "memory");  // Bs[0] writes done
    __builtin_amdgcn_s_barrier();                       // Bs[0] visible

    // ---- main loop: 1 barrier per k-step, 12 loads live across it ----
#pragma unroll 2
    for (int kt = 0; kt < KITER; ++kt) {
        const int p = kt & 1, q = p ^ 1;

        // 1) issue next-tile A stage into As[q] (last-read at kt-1, safe)
        {
            const int k1 = (kt + 1 < KITER ? kt + 1 : KITER - 1) * 32;
#pragma unroll
            for (int i = 0; i < 4; ++i) gl_lds16(wrow[i] + k1, lA[q][i]);
        }
        // 2) issue gather for tile kt+2 into v[p]
        {
            const int k2 = (kt + 2 < KITER ? kt + 2 : KITER - 1) * 32;
            int4 k4 = *(const int4*)&koS[k2 + ks];
#pragma unroll
            for (int ry = 0; ry < 2; ++ry)
#pragma unroll
                for (int j = 0; j < 4; ++j)
                    v[p][ry][j] = x[basex[ry] + ((const int*)&k4)[j]];
        }
        // 3) counted drain: keep this step's 12; complete prev gl(kt)+ga(kt+1)
        asm volatile("s_waitcnt vmcnt(12)" ::: "memory");
        // 4) pack tile kt+1's gathered x -> Bs[q]
#pragma unroll
        for (int ry = 0; ry < 2; ++ry) {
            unsigned int u0 = (unsigned int)f2bf(v[q][ry][0]) |
                              ((unsigned int)f2bf(v[q][ry][1]) << 16);
            unsigned int u1 = (unsigned int)f2bf(v[q][ry][2]) |
                              ((unsigned int)f2bf(v[q][ry][3]) << 16);
            uint2 pk; pk.x = u0; pk.y = u1;
            *reinterpret_cast<uint2*>(bW[q] + ry * 32 * BSTR) = pk;
        }
        // 5) compute tile kt from buffer p: 4 a-frags x 4 b-frags = 16 MFMA
        bf16x8 a[4], b[4];
#pragma unroll
        for (int ms = 0; ms < 4; ++ms)
            a[ms] = *(const bf16x8*)(aB[p] + ms * 16 * 32);
#pragma unroll
        for (int ns = 0; ns < 4; ++ns)
            b[ns] = *(const bf16x8*)(bB[p] + ns * 16 * BSTR);
#pragma unroll
        for (int ms = 0; ms < 4; ++ms)
#pragma unroll
            for (int ns = 0; ns < 4; ++ns)
                acc[ms][ns] = __builtin_amdgcn_mfma_f32_16x16x32_bf16(
                    a[ms], b[ns], acc[ms][ns], 0, 0, 0);
        // 6) cross-wave Bs visibility only; NO vmcnt drain at the barrier.
        asm volatile("s_waitcnt lgkmcnt(0)" ::: "memory");
        __builtin_amdgcn_s_barrier();
    }

    // Epilogue: D row = o (quad*4+r), col = m (lane&15).
#pragma unroll
    for (int ns = 0; ns < 4; ++ns) {
        const int mh  = mBase + ns * 16 + lo;
        const int xwe = mh & 31;
        const int ryg = mh >> 5;
        const int n = ryg / 30, y = ryg - n * 30;
        if (xwe < OW) {
            const size_t ob = (size_t)n * (OUTC * OUT_SP) + (size_t)y * OW + xwe;
#pragma unroll
            for (int ms = 0; ms < 4; ++ms) {
                const int o0 = oBase + wave * 64 + ms * 16 + quad * 4;
#pragma unroll
                for (int r = 0; r < 4; ++r)
                    out[ob + (size_t)(o0 + r) * OUT_SP] = acc[ms][ns][r];
            }
        }
    }
}

// ---------------------------------------------------------------------------
extern "C" void kernel_launch(void* const* d_in, const int* in_sizes, int n_in,
                              void* d_out, int out_size, void* d_ws, size_t ws_size,
                              hipStream_t stream) {
    const float* x   = (const float*)d_in[0];
    const float* w   = (const float*)d_in[1];
    const int*   idx = (const int*)d_in[2];
    float*       out = (float*)d_out;

    // ws layout: koff 4608B | wT bf16 1179648B  (~1.2 MB total)
    char* ws = (char*)d_ws;
    int*            koff = (int*)ws;
    unsigned short* wT   = (unsigned short*)(ws + 4608);

    prep_kernel<<<dim3(K_SEL / 32, OUTC / 32), dim3(256), 0, stream>>>(idx, w, koff, wT);
    gemm_kernel<<<dim3(NMT * NOT), dim3(256), 0, stream>>>(wT, x, koff, out);
}